// Round 9
// baseline (7209.270 us; speedup 1.0000x reference)
//
#include <hip/hip_runtime.h>
#include <hip/hip_bf16.h>
#include <math.h>

#define DIMX 512
#define NTOK 85
#define BATCH 1024
#define M_ROWS (BATCH * NTOK)   // 87040
#define MLP_H 2048
#define DEPTH 6

typedef __attribute__((ext_vector_type(8))) short short8;
typedef __attribute__((ext_vector_type(4))) float f32x4;

__device__ inline float bf2f(ushort u) {
    union { unsigned int i; float f; } v; v.i = ((unsigned int)u) << 16; return v.f;
}
__device__ inline ushort f2bf(float f) {
    __hip_bfloat16 h = __float2bfloat16(f);
    union { __hip_bfloat16 h; ushort u; } v; v.h = h; return v.u;
}
__device__ inline unsigned int pack2(float a, float b) {
    return (unsigned int)f2bf(a) | ((unsigned int)f2bf(b) << 16);
}
// cheap GELU: v * sigmoid(1.5957691*(v + 0.044715 v^3)); max abs err ~5e-4 (< bf16 ulp there)
__device__ inline float gelu_fast(float v) {
    float u = 1.5957691f * fmaf(0.044715f * v, v * v, v);
    return v / (1.0f + __expf(-u));
}

// async global->LDS, 16B per lane. lds dest must be wave-uniform; HW adds lane*16.
__device__ inline void gload16(const ushort* g, ushort* lds) {
    __builtin_amdgcn_global_load_lds(
        (const __attribute__((address_space(1))) unsigned int*)g,
        (__attribute__((address_space(3))) unsigned int*)lds, 16, 0, 0);
}

// ---------------- weight transpose + convert: in [K][N] f32 -> out [N][K] bf16
__global__ __launch_bounds__(256) void transpose_bf16(const float* __restrict__ in,
                                                      ushort* __restrict__ out,
                                                      int K, int N) {
    __shared__ float tile[32][33];
    int n0 = blockIdx.x * 32, k0 = blockIdx.y * 32;
    int tx = threadIdx.x, ty = threadIdx.y;   // 32 x 8
    #pragma unroll
    for (int j = 0; j < 32; j += 8)
        tile[ty + j][tx] = in[(size_t)(k0 + ty + j) * N + n0 + tx];
    __syncthreads();
    #pragma unroll
    for (int j = 0; j < 32; j += 8)
        out[(size_t)(n0 + ty + j) * K + k0 + tx] = f2bf(tile[tx][ty + j]);
}

// ---------------- RoPE cos/sin table
__global__ void rope_table(const float* __restrict__ coords, float* __restrict__ tab) {
    int t = blockIdx.x;       // 0..83
    int idx = threadIdx.x;    // 0..15
    float freq = expf(-(float)idx * (2.302585093f / 16.0f));
    float twopi = 6.283185307179586f;
    float ax = coords[t * 2 + 0] * freq * twopi;
    float ay = coords[t * 2 + 1] * freq * twopi;
    tab[t * 64 + idx]      = cosf(ax);
    tab[t * 64 + 16 + idx] = sinf(ax);
    tab[t * 64 + 32 + idx] = cosf(ay);
    tab[t * 64 + 48 + idx] = sinf(ay);
}

// ---------------- LayerNorm: f32 row of 512 -> bf16 out, wave per row
__global__ __launch_bounds__(256) void ln_kernel(const float* __restrict__ x,
                                                 const float* __restrict__ g,
                                                 const float* __restrict__ bta,
                                                 ushort* __restrict__ out) {
    int w = threadIdx.x >> 6, lane = threadIdx.x & 63;
    size_t row = (size_t)blockIdx.x * 4 + w;
    const float* xr = x + row * DIMX;
    int c = lane * 8;
    float4 v0 = *(const float4*)(xr + c);
    float4 v1 = *(const float4*)(xr + c + 4);
    float s = v0.x + v0.y + v0.z + v0.w + v1.x + v1.y + v1.z + v1.w;
    #pragma unroll
    for (int m = 32; m; m >>= 1) s += __shfl_xor(s, m);
    float mu = s * (1.0f / 512.0f);
    float d0 = v0.x - mu, d1 = v0.y - mu, d2 = v0.z - mu, d3 = v0.w - mu;
    float d4 = v1.x - mu, d5 = v1.y - mu, d6 = v1.z - mu, d7 = v1.w - mu;
    float q = d0*d0 + d1*d1 + d2*d2 + d3*d3 + d4*d4 + d5*d5 + d6*d6 + d7*d7;
    #pragma unroll
    for (int m = 32; m; m >>= 1) q += __shfl_xor(q, m);
    float rs = rsqrtf(q * (1.0f / 512.0f) + 1e-5f);
    float4 g0 = *(const float4*)(g + c), g1 = *(const float4*)(g + c + 4);
    float4 b0 = *(const float4*)(bta + c), b1 = *(const float4*)(bta + c + 4);
    uint4 o;
    o.x = pack2(d0 * rs * g0.x + b0.x, d1 * rs * g0.y + b0.y);
    o.y = pack2(d2 * rs * g0.z + b0.z, d3 * rs * g0.w + b0.w);
    o.z = pack2(d4 * rs * g1.x + b1.x, d5 * rs * g1.y + b1.y);
    o.w = pack2(d6 * rs * g1.z + b1.z, d7 * rs * g1.w + b1.w);
    *(uint4*)&out[row * DIMX + c] = o;
}

// ---------------- GEMM class B ring-3 (proven, r5/r8): 256x128 tile, BK=32,
// ring-3 LDS (72 KB), 4 waves (2M x 2N), wave tile 128x64 -> 2 blocks/CU.
// EPI 0: bf16 rope(acc+bias); EPI 1: f32 = inF + acc+bias; EPI 2: bf16 gelu
template <int EPI>
__global__ __launch_bounds__(256, 2) void gemm_wide(const ushort* __restrict__ A,
                                                    const ushort* __restrict__ Bt,
                                                    const float* __restrict__ bias,
                                                    const float* __restrict__ inF,
                                                    float* __restrict__ outF,
                                                    ushort* __restrict__ outB,
                                                    int M, int N, int K,
                                                    const float* __restrict__ tab) {
    __shared__ ushort AsF[3 * 8192] __attribute__((aligned(16)));  // ring-3, 48 KB
    __shared__ ushort BsF[3 * 4096] __attribute__((aligned(16)));  // ring-3, 24 KB
    int tid = threadIdx.x;
    int w = tid >> 6, lane = tid & 63;
    int wm2 = (w >> 1) * 128;   // 0 or 128
    int wn = (w & 1) * 64;      // 0 or 64

    // ---- bijective XCD swizzle (m204)
    int nbx = gridDim.x;
    int nwg = nbx * gridDim.y;
    int orig = blockIdx.y * nbx + blockIdx.x;
    int q8 = nwg >> 3, r8 = nwg & 7;
    int xcd = orig & 7, loc = orig >> 3;
    int id = (xcd < r8) ? xcd * (q8 + 1) + loc : r8 * (q8 + 1) + (xcd - r8) * q8 + loc;
    int m0 = (id / nbx) * 256;
    int n0 = (id % nbx) * 128;

    int srow = tid >> 2;                          // 0..63
    int scol = ((tid & 3) ^ ((srow >> 1) & 3)) * 8;
    int rA0 = m0 + srow;       if (rA0 >= M) rA0 = M - 1;
    int rA1 = m0 + 64 + srow;  if (rA1 >= M) rA1 = M - 1;
    int rA2 = m0 + 128 + srow; if (rA2 >= M) rA2 = M - 1;
    int rA3 = m0 + 192 + srow; if (rA3 >= M) rA3 = M - 1;
    const ushort* gA0 = A + (size_t)rA0 * K + scol;
    const ushort* gA1 = A + (size_t)rA1 * K + scol;
    const ushort* gA2 = A + (size_t)rA2 * K + scol;
    const ushort* gA3 = A + (size_t)rA3 * K + scol;
    const ushort* gB0 = Bt + (size_t)(n0 + srow) * K + scol;
    const ushort* gB1 = Bt + (size_t)(n0 + 64 + srow) * K + scol;
    int dwz = w * 512;
    int swA = 0, swB = 0;

#define STAGEW() do {                                                          \
        gload16(gA0, &AsF[swA + dwz]);                                         \
        gload16(gA1, &AsF[swA + 2048 + dwz]);                                  \
        gload16(gA2, &AsF[swA + 4096 + dwz]);                                  \
        gload16(gA3, &AsF[swA + 6144 + dwz]);                                  \
        gload16(gB0, &BsF[swB + dwz]);                                         \
        gload16(gB1, &BsF[swB + 2048 + dwz]);                                  \
        gA0 += 32; gA1 += 32; gA2 += 32; gA3 += 32; gB0 += 32; gB1 += 32;      \
        swA += 8192; if (swA == 24576) swA = 0;                                \
        swB += 4096; if (swB == 12288) swB = 0; } while (0)

    int l15 = lane & 15, lq = lane >> 4;
    int sw = (lq ^ ((l15 >> 1) & 3)) * 8;
    int aoff = (wm2 + l15) * 32 + sw;
    int boff = (wn + l15) * 32 + sw;
    int roffA = 0, roffB = 0;

    int NT = K >> 5;
    STAGEW(); STAGEW();

    f32x4 acc[8][4] = {};

    for (int t = 0; t < NT; ++t) {
        if (t < NT - 1) asm volatile("s_waitcnt vmcnt(6)" ::: "memory");
        else            asm volatile("s_waitcnt vmcnt(0)" ::: "memory");
        __builtin_amdgcn_s_barrier();
        short8 a[8], b[4];
        #pragma unroll
        for (int i = 0; i < 8; i++) a[i] = *(const short8*)&AsF[roffA + aoff + i * 512];
        #pragma unroll
        for (int j = 0; j < 4; j++) b[j] = *(const short8*)&BsF[roffB + boff + j * 512];
        if (t + 2 < NT) STAGEW();
        __builtin_amdgcn_s_setprio(1);
        #pragma unroll
        for (int i = 0; i < 8; i++)
            #pragma unroll
            for (int j = 0; j < 4; j++)
                acc[i][j] = __builtin_amdgcn_mfma_f32_16x16x32_bf16(a[i], b[j], acc[i][j], 0, 0, 0);
        __builtin_amdgcn_s_setprio(0);
        roffA += 8192; if (roffA == 24576) roffA = 0;
        roffB += 4096; if (roffB == 12288) roffB = 0;
    }
#undef STAGEW

    int cr = lq * 4;
    int cc = l15;
    if (EPI == 0) {
        bool ropeReg = (n0 + wn) < 1024;
        int gnb = n0 + wn + cc;
        float bb0 = bias[gnb], bb1 = bias[gnb + 16], bb2 = bias[gnb + 32], bb3 = bias[gnb + 48];
        #pragma unroll
        for (int i = 0; i < 8; i++) {
            #pragma unroll
            for (int rr = 0; rr < 4; rr++) {
                int gm = m0 + wm2 + i * 16 + cr + rr;
                if (gm >= M) continue;
                int n = gm % NTOK;
                float v0 = acc[i][0][rr] + bb0;
                float v1 = acc[i][1][rr] + bb1;
                float v2 = acc[i][2][rr] + bb2;
                float v3 = acc[i][3][rr] + bb3;
                if (ropeReg && n > 0) {
                    const float* tt = tab + (size_t)(n - 1) * 64 + cc;
                    float cx = tt[0], sx = tt[16], cy = tt[32], sy = tt[48];
                    float y0 = v0 * cx - v1 * sx;
                    float y1 = v0 * sx + v1 * cx;
                    float y2 = v2 * cy - v3 * sy;
                    float y3 = v2 * sy + v3 * cy;
                    v0 = y0; v1 = y1; v2 = y2; v3 = y3;
                }
                size_t o = (size_t)gm * N + gnb;
                outB[o]      = f2bf(v0);
                outB[o + 16] = f2bf(v1);
                outB[o + 32] = f2bf(v2);
                outB[o + 48] = f2bf(v3);
            }
        }
    } else {
        #pragma unroll
        for (int i = 0; i < 8; i++) {
            #pragma unroll
            for (int rr = 0; rr < 4; rr++) {
                int gm = m0 + wm2 + i * 16 + cr + rr;
                if (gm >= M) continue;
                #pragma unroll
                for (int j = 0; j < 4; j++) {
                    int gn = n0 + wn + j * 16 + cc;
                    float v = acc[i][j][rr] + bias[gn];
                    size_t o = (size_t)gm * N + gn;
                    if (EPI == 1) {
                        outF[o] = inF[o] + v;
                    } else {
                        outB[o] = f2bf(gelu_fast(v));
                    }
                }
            }
        }
    }
}

// ---------------- GEMM class NB (barrier-free probe, FC1): 192x128 block tile,
// 4 waves each owning a PRIVATE 96x64 output tile with PRIVATE per-wave LDS
// (A 96x32 ring-2 + B 64x32 ring-2 = 20 KB/wave, 80 KB/block -> 2 blocks/CU).
// NO s_barrier in the K-loop: each wave self-syncs on its OWN vmcnt FIFO.
//   iter t: [lgkm guard] issue STAGE(t+1) -> vmcnt(10) (leaves the 10 new
//   loads in flight = one full step of latency cover) -> ds_read slot t&1 ->
//   24 MFMA. Ring-2 safe per-wave: slot (t+1)&1 was read at t-1 by this wave
//   and consumed by its MFMAs (compiler lgkm waits) before the overwrite.
// acc[6][4] = 96 AGPR + ~90 VGPR -> 2 waves/SIMD. Same verified chunk-xor
// swizzle (row-parity bits unaffected by 16-row frag offsets).
__global__ __launch_bounds__(256, 2) void gemm_nb(const ushort* __restrict__ A,
                                                  const ushort* __restrict__ Bt,
                                                  const float* __restrict__ bias,
                                                  ushort* __restrict__ outB,
                                                  int M, int N, int K) {
    __shared__ ushort LDS[4 * 10240] __attribute__((aligned(16)));  // 80 KB
    int tid = threadIdx.x;
    int w = tid >> 6, lane = tid & 63;
    int wm = (w >> 1) * 96;    // 0 or 96
    int wn = (w & 1) * 64;     // 0 or 64

    // ---- bijective XCD swizzle (m204)
    int nbx = gridDim.x;
    int nwg = nbx * gridDim.y;
    int orig = blockIdx.y * nbx + blockIdx.x;
    int q8 = nwg >> 3, r8 = nwg & 7;
    int xcd = orig & 7, loc = orig >> 3;
    int id = (xcd < r8) ? xcd * (q8 + 1) + loc : r8 * (q8 + 1) + (xcd - r8) * q8 + loc;
    int m0 = (id / nbx) * 192;
    int n0 = (id % nbx) * 128;

    // ---- per-wave staging addresses: lane covers row i*16 + (lane>>2),
    //      swizzled chunk (lane&3)^(((lane>>2)>>1)&3) -- independent of i.
    int srow = lane >> 2;                               // 0..15
    int scol = ((lane & 3) ^ ((srow >> 1) & 3)) * 8;
    const ushort* pA[6];
    const ushort* pB[4];
    #pragma unroll
    for (int i = 0; i < 6; i++) {
        int r = m0 + wm + i * 16 + srow; if (r >= M) r = M - 1;
        pA[i] = A + (size_t)r * K + scol;
    }
    #pragma unroll
    for (int j = 0; j < 4; j++)
        pB[j] = Bt + (size_t)(n0 + wn + j * 16 + srow) * K + scol;

    ushort* LW = &LDS[w * 10240];   // private: A0[0) A1[3072) B0[6144) B1[8192)

#define STAGE_NB(T) do { int kc = (T) * 32, s = ((T) & 1);                     \
        int da = s * 3072, db = 6144 + s * 2048;                               \
        gload16(pA[0] + kc, &LW[da]);                                          \
        gload16(pA[1] + kc, &LW[da + 512]);                                    \
        gload16(pA[2] + kc, &LW[da + 1024]);                                   \
        gload16(pA[3] + kc, &LW[da + 1536]);                                   \
        gload16(pA[4] + kc, &LW[da + 2048]);                                   \
        gload16(pA[5] + kc, &LW[da + 2560]);                                   \
        gload16(pB[0] + kc, &LW[db]);                                          \
        gload16(pB[1] + kc, &LW[db + 512]);                                    \
        gload16(pB[2] + kc, &LW[db + 1024]);                                   \
        gload16(pB[3] + kc, &LW[db + 1536]); } while (0)

    // ---- fragment read offsets (wave-local rows, same swizzle)
    int l15 = lane & 15, lq = lane >> 4;
    int sw = (lq ^ ((l15 >> 1) & 3)) * 8;
    int foff = l15 * 32 + sw;

    int NT = K >> 5;
    STAGE_NB(0);

    f32x4 acc[6][4] = {};

    for (int t = 0; t < NT; ++t) {
        int ra = (t & 1) * 3072, rb = 6144 + (t & 1) * 2048;
        if (t + 1 < NT) {
            asm volatile("s_waitcnt lgkmcnt(0)" ::: "memory");  // prior-slot reads drained
            STAGE_NB(t + 1);
            asm volatile("s_waitcnt vmcnt(10)" ::: "memory");   // stage(t) landed
        } else {
            asm volatile("s_waitcnt vmcnt(0)" ::: "memory");
        }
        short8 a[6], b[4];
        #pragma unroll
        for (int i = 0; i < 6; i++) a[i] = *(const short8*)&LW[ra + foff + i * 512];
        #pragma unroll
        for (int j = 0; j < 4; j++) b[j] = *(const short8*)&LW[rb + foff + j * 512];
        __builtin_amdgcn_s_setprio(1);
        #pragma unroll
        for (int i = 0; i < 6; i++)
            #pragma unroll
            for (int j = 0; j < 4; j++)
                acc[i][j] = __builtin_amdgcn_mfma_f32_16x16x32_bf16(a[i], b[j], acc[i][j], 0, 0, 0);
        __builtin_amdgcn_s_setprio(0);
    }
#undef STAGE_NB

    // ---- epilogue (bias + gelu -> bf16); C frag: row = lq*4+rr, col = l15
    int cr = lq * 4;
    int cc = l15;
    #pragma unroll
    for (int i = 0; i < 6; i++) {
        #pragma unroll
        for (int rr = 0; rr < 4; rr++) {
            int gm = m0 + wm + i * 16 + cr + rr;
            if (gm >= M) continue;
            #pragma unroll
            for (int j = 0; j < 4; j++) {
                int gn = n0 + wn + j * 16 + cc;
                float v = acc[i][j][rr] + bias[gn];
                outB[(size_t)gm * N + gn] = f2bf(gelu_fast(v));
            }
        }
    }
}

// ---------------- MFMA attention: block = (batch,head), 384 threads = 6 waves.
__global__ __launch_bounds__(384) void attn_kernel(const ushort* __restrict__ qkv,
                                                   ushort* __restrict__ out) {
    __shared__ ushort SU[13824] __attribute__((aligned(16)));  // Qb | Kb, later Pb
    __shared__ ushort Vt[6656]  __attribute__((aligned(16)));  // V^T [64][104]
    int bh = blockIdx.x;
    int b = bh >> 3, h = bh & 7;
    int tid = threadIdx.x;
    size_t base = (size_t)b * NTOK * 1536 + h * 64;

    for (int it = tid; it < 1536; it += 384) {
        int mat = (it >= 768) ? 1 : 0;
        int item = it - mat * 768;
        int n = item >> 3, g = item & 7;
        short8 v = {};
        if (n < NTOK)
            v = *(const short8*)&qkv[base + (size_t)n * 1536 + mat * 512 + g * 8];
        *(short8*)&SU[mat * 6912 + n * 72 + g * 8] = v;
    }
    for (int it = tid; it < 768; it += 384) {
        int n = it % 96;
        int d0 = (it / 96) * 8;
        short8 v = {};
        if (n < NTOK)
            v = *(const short8*)&qkv[base + (size_t)n * 1536 + 1024 + d0];
        #pragma unroll
        for (int j = 0; j < 8; j++)
            Vt[(d0 + j) * 104 + n] = (ushort)v[j];
    }
    __syncthreads();

    int wid = tid >> 6;
    int lane = tid & 63;
    int q = lane >> 4, c = lane & 15;
    int i0 = wid * 16;

    f32x4 acc[6] = {};
    #pragma unroll
    for (int kk = 0; kk < 2; kk++) {
        short8 aq = *(const short8*)&SU[(i0 + c) * 72 + kk * 32 + q * 8];
        #pragma unroll
        for (int t = 0; t < 6; t++) {
            short8 bk = *(const short8*)&SU[6912 + (t * 16 + c) * 72 + kk * 32 + q * 8];
            acc[t] = __builtin_amdgcn_mfma_f32_16x16x32_bf16(aq, bk, acc[t], 0, 0, 0);
        }
    }
    __syncthreads();

    #pragma unroll
    for (int r = 0; r < 4; r++) {
        int i = i0 + q * 4 + r;
        int si = (i == 0) ? 3 : (i < 5 ? 1 : (i < 21 ? 2 : 3));
        float vs[6];
        float m = -1e30f;
        #pragma unroll
        for (int t = 0; t < 6; t++) {
            int j = t * 16 + c;
            int sj = (j == 0) ? si : (j < 5 ? 1 : (j < 21 ? 2 : (j < NTOK ? 3 : -1)));
            float v = (sj == si) ? acc[t][r] * 0.125f : -1e30f;
            vs[t] = v;
            m = fmaxf(m, v);
        }
        #pragma unroll
        for (int mk = 8; mk; mk >>= 1) m = fmaxf(m, __shfl_xor(m, mk));
        float s = 0.f, ps[6];
        #pragma unroll
        for (int t = 0; t < 6; t++) { ps[t] = __expf(vs[t] - m); s += ps[t]; }
        #pragma unroll
        for (int mk = 8; mk; mk >>= 1) s += __shfl_xor(s, mk);
        float inv = 1.0f / s;
        #pragma unroll
        for (int t = 0; t < 6; t++)
            SU[i * 104 + t * 16 + c] = f2bf(ps[t] * inv);
    }
    __syncthreads();

    f32x4 o2[4] = {};
    #pragma unroll
    for (int kk = 0; kk < 3; kk++) {
        short8 ap = *(const short8*)&SU[(i0 + c) * 104 + kk * 32 + q * 8];
        #pragma unroll
        for (int nt = 0; nt < 4; nt++) {
            short8 bv = *(const short8*)&Vt[(nt * 16 + c) * 104 + kk * 32 + q * 8];
            o2[nt] = __builtin_amdgcn_mfma_f32_16x16x32_bf16(ap, bv, o2[nt], 0, 0, 0);
        }
    }
    size_t orow = (size_t)b * NTOK;
    #pragma unroll
    for (int nt = 0; nt < 4; nt++) {
        #pragma unroll
        for (int r = 0; r < 4; r++) {
            int i = i0 + q * 4 + r;
            if (i < NTOK)
                out[(orow + i) * DIMX + h * 64 + nt * 16 + c] = f2bf(o2[nt][r]);
        }
    }
}

extern "C" void kernel_launch(void* const* d_in, const int* in_sizes, int n_in,
                              void* d_out, int out_size, void* d_ws, size_t ws_size,
                              hipStream_t stream) {
    const float* x_in    = (const float*)d_in[0];
    const float* coords  = (const float*)d_in[1];
    const float* ln1_g   = (const float*)d_in[2];
    const float* ln1_b   = (const float*)d_in[3];
    const float* qkv_w   = (const float*)d_in[4];
    const float* qkv_b   = (const float*)d_in[5];
    const float* proj_w  = (const float*)d_in[6];
    const float* proj_b  = (const float*)d_in[7];
    const float* ln2_g   = (const float*)d_in[8];
    const float* ln2_b   = (const float*)d_in[9];
    const float* fc1_w   = (const float*)d_in[10];
    const float* fc1_b   = (const float*)d_in[11];
    const float* fc2_w   = (const float*)d_in[12];
    const float* fc2_b   = (const float*)d_in[13];

    char* ws = (char*)d_ws;
    size_t off = 0;
    auto alloc = [&](size_t bytes) -> void* {
        void* p = ws + off;
        off += (bytes + 255) & ~(size_t)255;
        return p;
    };
    auto asz = [](size_t b) { return (b + 255) & ~(size_t)255; };

    const size_t WPL = 512 * 1536 + 512 * 512 + 512 * 2048 + 2048 * 512; // 3,145,728

    size_t fixed = asz(WPL * DEPTH * sizeof(ushort)) + asz(84 * 64 * sizeof(float));
    int Bc = 1024;
    while (Bc > 4) {
        size_t rc = (size_t)Bc * NTOK;
        size_t need = fixed + asz(rc * DIMX * sizeof(ushort)) + asz(rc * MLP_H * sizeof(ushort));
        if (need <= ws_size) break;
        Bc >>= 1;
    }
    size_t Rc = (size_t)Bc * NTOK;

    ushort* wt   = (ushort*)alloc(WPL * DEPTH * sizeof(ushort));
    float*  tab  = (float*)alloc(84 * 64 * sizeof(float));
    ushort* hbuf = (ushort*)alloc(Rc * DIMX * sizeof(ushort));   // ln out / attn out (aliased)
    ushort* big  = (ushort*)alloc(Rc * MLP_H * sizeof(ushort));  // qkv out / mlp out (aliased)

    rope_table<<<84, 16, 0, stream>>>(coords, tab);

    dim3 tb(32, 8);
    for (int l = 0; l < DEPTH; l++) {
        ushort* wl = wt + (size_t)l * WPL;
        transpose_bf16<<<dim3(1536 / 32, 512 / 32), tb, 0, stream>>>(
            qkv_w + (size_t)l * 512 * 1536, wl, 512, 1536);
        transpose_bf16<<<dim3(512 / 32, 512 / 32), tb, 0, stream>>>(
            proj_w + (size_t)l * 512 * 512, wl + 786432, 512, 512);
        transpose_bf16<<<dim3(2048 / 32, 512 / 32), tb, 0, stream>>>(
            fc1_w + (size_t)l * 512 * 2048, wl + 1048576, 512, 2048);
        transpose_bf16<<<dim3(512 / 32, 2048 / 32), tb, 0, stream>>>(
            fc2_w + (size_t)l * 2048 * 512, wl + 2097152, 2048, 512);
    }

    int mt256 = (int)(Rc / 256);
    int mt192 = (int)((Rc + 191) / 192);
    int lnblocks = (int)(Rc / 4);
    for (int c = 0; c < BATCH / Bc; c++) {
        float* xc = (float*)d_out + (size_t)c * Rc * DIMX;
        const float* xin_c = x_in + (size_t)c * Rc * DIMX;
        int Mc = (int)Rc;
        for (int l = 0; l < DEPTH; l++) {
            ushort* wl = wt + (size_t)l * WPL;
            // layer 0 reads the input tensor directly (no startup memcpy);
            // proj of layer 0 writes residual x_in + proj into xc.
            const float* xsrc = (l == 0) ? xin_c : xc;
            ln_kernel<<<lnblocks, 256, 0, stream>>>(
                xsrc, ln1_g + l * 512, ln1_b + l * 512, hbuf);
            gemm_wide<0><<<dim3(1536 / 128, mt256), 256, 0, stream>>>(
                hbuf, wl, qkv_b + (size_t)l * 1536, nullptr, nullptr, big,
                Mc, 1536, 512, tab);
            attn_kernel<<<Bc * 8, 384, 0, stream>>>(big, hbuf);
            gemm_wide<1><<<dim3(512 / 128, mt256), 256, 0, stream>>>(
                hbuf, wl + 786432, proj_b + (size_t)l * 512, xsrc, xc, nullptr,
                Mc, 512, 512, nullptr);
            ln_kernel<<<lnblocks, 256, 0, stream>>>(
                xc, ln2_g + l * 512, ln2_b + l * 512, hbuf);
            // FC1: barrier-free probe kernel (A/B vs FC2's class-B, equal FLOP)
            gemm_nb<<<dim3(2048 / 128, mt192), 256, 0, stream>>>(
                hbuf, wl + 1048576, fc1_b + (size_t)l * 2048, big,
                Mc, 2048, 512);
            gemm_wide<1><<<dim3(512 / 128, mt256), 256, 0, stream>>>(
                big, wl + 2097152, fc2_b + (size_t)l * 512, xc, xc, nullptr,
                Mc, 512, 2048, nullptr);
        }
    }
}

// Round 10
// 6811.712 us; speedup vs baseline: 1.0584x; 1.0584x over previous
//
#include <hip/hip_runtime.h>
#include <hip/hip_bf16.h>
#include <math.h>

#define DIMX 512
#define NTOK 85
#define BATCH 1024
#define M_ROWS (BATCH * NTOK)   // 87040
#define MLP_H 2048
#define DEPTH 6

typedef __attribute__((ext_vector_type(8))) short short8;
typedef __attribute__((ext_vector_type(4))) float f32x4;

__device__ inline float bf2f(ushort u) {
    union { unsigned int i; float f; } v; v.i = ((unsigned int)u) << 16; return v.f;
}
__device__ inline ushort f2bf(float f) {
    __hip_bfloat16 h = __float2bfloat16(f);
    union { __hip_bfloat16 h; ushort u; } v; v.h = h; return v.u;
}
__device__ inline unsigned int pack2(float a, float b) {
    return (unsigned int)f2bf(a) | ((unsigned int)f2bf(b) << 16);
}
// cheap GELU: v * sigmoid(1.5957691*(v + 0.044715 v^3)); max abs err ~5e-4 (< bf16 ulp there)
__device__ inline float gelu_fast(float v) {
    float u = 1.5957691f * fmaf(0.044715f * v, v * v, v);
    return v / (1.0f + __expf(-u));
}

// async global->LDS, 16B per lane. lds dest must be wave-uniform; HW adds lane*16.
__device__ inline void gload16(const ushort* g, ushort* lds) {
    __builtin_amdgcn_global_load_lds(
        (const __attribute__((address_space(1))) unsigned int*)g,
        (__attribute__((address_space(3))) unsigned int*)lds, 16, 0, 0);
}

// ---------------- weight transpose + convert: in [K][N] f32 -> out [N][K] bf16
__global__ __launch_bounds__(256) void transpose_bf16(const float* __restrict__ in,
                                                      ushort* __restrict__ out,
                                                      int K, int N) {
    __shared__ float tile[32][33];
    int n0 = blockIdx.x * 32, k0 = blockIdx.y * 32;
    int tx = threadIdx.x, ty = threadIdx.y;   // 32 x 8
    #pragma unroll
    for (int j = 0; j < 32; j += 8)
        tile[ty + j][tx] = in[(size_t)(k0 + ty + j) * N + n0 + tx];
    __syncthreads();
    #pragma unroll
    for (int j = 0; j < 32; j += 8)
        out[(size_t)(n0 + ty + j) * K + k0 + tx] = f2bf(tile[tx][ty + j]);
}

// ---------------- RoPE cos/sin table
__global__ void rope_table(const float* __restrict__ coords, float* __restrict__ tab) {
    int t = blockIdx.x;       // 0..83
    int idx = threadIdx.x;    // 0..15
    float freq = expf(-(float)idx * (2.302585093f / 16.0f));
    float twopi = 6.283185307179586f;
    float ax = coords[t * 2 + 0] * freq * twopi;
    float ay = coords[t * 2 + 1] * freq * twopi;
    tab[t * 64 + idx]      = cosf(ax);
    tab[t * 64 + 16 + idx] = sinf(ax);
    tab[t * 64 + 32 + idx] = cosf(ay);
    tab[t * 64 + 48 + idx] = sinf(ay);
}

// ---------------- LayerNorm: f32 row of 512 -> bf16 out, wave per row
__global__ __launch_bounds__(256) void ln_kernel(const float* __restrict__ x,
                                                 const float* __restrict__ g,
                                                 const float* __restrict__ bta,
                                                 ushort* __restrict__ out) {
    int w = threadIdx.x >> 6, lane = threadIdx.x & 63;
    size_t row = (size_t)blockIdx.x * 4 + w;
    const float* xr = x + row * DIMX;
    int c = lane * 8;
    float4 v0 = *(const float4*)(xr + c);
    float4 v1 = *(const float4*)(xr + c + 4);
    float s = v0.x + v0.y + v0.z + v0.w + v1.x + v1.y + v1.z + v1.w;
    #pragma unroll
    for (int m = 32; m; m >>= 1) s += __shfl_xor(s, m);
    float mu = s * (1.0f / 512.0f);
    float d0 = v0.x - mu, d1 = v0.y - mu, d2 = v0.z - mu, d3 = v0.w - mu;
    float d4 = v1.x - mu, d5 = v1.y - mu, d6 = v1.z - mu, d7 = v1.w - mu;
    float q = d0*d0 + d1*d1 + d2*d2 + d3*d3 + d4*d4 + d5*d5 + d6*d6 + d7*d7;
    #pragma unroll
    for (int m = 32; m; m >>= 1) q += __shfl_xor(q, m);
    float rs = rsqrtf(q * (1.0f / 512.0f) + 1e-5f);
    float4 g0 = *(const float4*)(g + c), g1 = *(const float4*)(g + c + 4);
    float4 b0 = *(const float4*)(bta + c), b1 = *(const float4*)(bta + c + 4);
    uint4 o;
    o.x = pack2(d0 * rs * g0.x + b0.x, d1 * rs * g0.y + b0.y);
    o.y = pack2(d2 * rs * g0.z + b0.z, d3 * rs * g0.w + b0.w);
    o.z = pack2(d4 * rs * g1.x + b1.x, d5 * rs * g1.y + b1.y);
    o.w = pack2(d6 * rs * g1.z + b1.z, d7 * rs * g1.w + b1.w);
    *(uint4*)&out[row * DIMX + c] = o;
}

// ---------------- GEMM class B ring-3 (proven, r5/r8): 256x128 tile, BK=32,
// ring-3 LDS (72 KB), 4 waves (2M x 2N), wave tile 128x64 -> 2 blocks/CU.
// EPI 0: bf16 rope(acc+bias); EPI 1: f32 = inF + acc+bias; EPI 2: bf16 gelu
template <int EPI>
__global__ __launch_bounds__(256, 2) void gemm_wide(const ushort* __restrict__ A,
                                                    const ushort* __restrict__ Bt,
                                                    const float* __restrict__ bias,
                                                    const float* __restrict__ inF,
                                                    float* __restrict__ outF,
                                                    ushort* __restrict__ outB,
                                                    int M, int N, int K,
                                                    const float* __restrict__ tab) {
    __shared__ ushort AsF[3 * 8192] __attribute__((aligned(16)));  // ring-3, 48 KB
    __shared__ ushort BsF[3 * 4096] __attribute__((aligned(16)));  // ring-3, 24 KB
    int tid = threadIdx.x;
    int w = tid >> 6, lane = tid & 63;
    int wm2 = (w >> 1) * 128;   // 0 or 128
    int wn = (w & 1) * 64;      // 0 or 64

    // ---- bijective XCD swizzle (m204)
    int nbx = gridDim.x;
    int nwg = nbx * gridDim.y;
    int orig = blockIdx.y * nbx + blockIdx.x;
    int q8 = nwg >> 3, r8 = nwg & 7;
    int xcd = orig & 7, loc = orig >> 3;
    int id = (xcd < r8) ? xcd * (q8 + 1) + loc : r8 * (q8 + 1) + (xcd - r8) * q8 + loc;
    int m0 = (id / nbx) * 256;
    int n0 = (id % nbx) * 128;

    int srow = tid >> 2;                          // 0..63
    int scol = ((tid & 3) ^ ((srow >> 1) & 3)) * 8;
    int rA0 = m0 + srow;       if (rA0 >= M) rA0 = M - 1;
    int rA1 = m0 + 64 + srow;  if (rA1 >= M) rA1 = M - 1;
    int rA2 = m0 + 128 + srow; if (rA2 >= M) rA2 = M - 1;
    int rA3 = m0 + 192 + srow; if (rA3 >= M) rA3 = M - 1;
    const ushort* gA0 = A + (size_t)rA0 * K + scol;
    const ushort* gA1 = A + (size_t)rA1 * K + scol;
    const ushort* gA2 = A + (size_t)rA2 * K + scol;
    const ushort* gA3 = A + (size_t)rA3 * K + scol;
    const ushort* gB0 = Bt + (size_t)(n0 + srow) * K + scol;
    const ushort* gB1 = Bt + (size_t)(n0 + 64 + srow) * K + scol;
    int dwz = w * 512;
    int swA = 0, swB = 0;

#define STAGEW() do {                                                          \
        gload16(gA0, &AsF[swA + dwz]);                                         \
        gload16(gA1, &AsF[swA + 2048 + dwz]);                                  \
        gload16(gA2, &AsF[swA + 4096 + dwz]);                                  \
        gload16(gA3, &AsF[swA + 6144 + dwz]);                                  \
        gload16(gB0, &BsF[swB + dwz]);                                         \
        gload16(gB1, &BsF[swB + 2048 + dwz]);                                  \
        gA0 += 32; gA1 += 32; gA2 += 32; gA3 += 32; gB0 += 32; gB1 += 32;      \
        swA += 8192; if (swA == 24576) swA = 0;                                \
        swB += 4096; if (swB == 12288) swB = 0; } while (0)

    int l15 = lane & 15, lq = lane >> 4;
    int sw = (lq ^ ((l15 >> 1) & 3)) * 8;
    int aoff = (wm2 + l15) * 32 + sw;
    int boff = (wn + l15) * 32 + sw;
    int roffA = 0, roffB = 0;

    int NT = K >> 5;
    STAGEW(); STAGEW();

    f32x4 acc[8][4] = {};

    for (int t = 0; t < NT; ++t) {
        if (t < NT - 1) asm volatile("s_waitcnt vmcnt(6)" ::: "memory");
        else            asm volatile("s_waitcnt vmcnt(0)" ::: "memory");
        __builtin_amdgcn_s_barrier();
        short8 a[8], b[4];
        #pragma unroll
        for (int i = 0; i < 8; i++) a[i] = *(const short8*)&AsF[roffA + aoff + i * 512];
        #pragma unroll
        for (int j = 0; j < 4; j++) b[j] = *(const short8*)&BsF[roffB + boff + j * 512];
        if (t + 2 < NT) STAGEW();
        __builtin_amdgcn_s_setprio(1);
        #pragma unroll
        for (int i = 0; i < 8; i++)
            #pragma unroll
            for (int j = 0; j < 4; j++)
                acc[i][j] = __builtin_amdgcn_mfma_f32_16x16x32_bf16(a[i], b[j], acc[i][j], 0, 0, 0);
        __builtin_amdgcn_s_setprio(0);
        roffA += 8192; if (roffA == 24576) roffA = 0;
        roffB += 4096; if (roffB == 12288) roffB = 0;
    }
#undef STAGEW

    int cr = lq * 4;
    int cc = l15;
    if (EPI == 0) {
        bool ropeReg = (n0 + wn) < 1024;
        int gnb = n0 + wn + cc;
        float bb0 = bias[gnb], bb1 = bias[gnb + 16], bb2 = bias[gnb + 32], bb3 = bias[gnb + 48];
        #pragma unroll
        for (int i = 0; i < 8; i++) {
            #pragma unroll
            for (int rr = 0; rr < 4; rr++) {
                int gm = m0 + wm2 + i * 16 + cr + rr;
                if (gm >= M) continue;
                int n = gm % NTOK;
                float v0 = acc[i][0][rr] + bb0;
                float v1 = acc[i][1][rr] + bb1;
                float v2 = acc[i][2][rr] + bb2;
                float v3 = acc[i][3][rr] + bb3;
                if (ropeReg && n > 0) {
                    const float* tt = tab + (size_t)(n - 1) * 64 + cc;
                    float cx = tt[0], sx = tt[16], cy = tt[32], sy = tt[48];
                    float y0 = v0 * cx - v1 * sx;
                    float y1 = v0 * sx + v1 * cx;
                    float y2 = v2 * cy - v3 * sy;
                    float y3 = v2 * sy + v3 * cy;
                    v0 = y0; v1 = y1; v2 = y2; v3 = y3;
                }
                size_t o = (size_t)gm * N + gnb;
                outB[o]      = f2bf(v0);
                outB[o + 16] = f2bf(v1);
                outB[o + 32] = f2bf(v2);
                outB[o + 48] = f2bf(v3);
            }
        }
    } else {
        #pragma unroll
        for (int i = 0; i < 8; i++) {
            #pragma unroll
            for (int rr = 0; rr < 4; rr++) {
                int gm = m0 + wm2 + i * 16 + cr + rr;
                if (gm >= M) continue;
                #pragma unroll
                for (int j = 0; j < 4; j++) {
                    int gn = n0 + wn + j * 16 + cc;
                    float v = acc[i][j][rr] + bias[gn];
                    size_t o = (size_t)gm * N + gn;
                    if (EPI == 1) {
                        outF[o] = inF[o] + v;
                    } else {
                        outB[o] = f2bf(gelu_fast(v));
                    }
                }
            }
        }
    }
}

// ---------------- GEMM class E (probe, FC1): 256x128 tile, BK=32, ring-3 LDS
// (72 KB), 512 threads = 8 waves (4M x 2N), wave tile 64x64 (acc[4][4] = 64
// AGPR + ~60 VGPR = class-A working set -> 4 waves/SIMD -> 16 waves/CU,
// 2 blocks co-resident). Class B's block traffic ratio at class A's occupancy.
// Staging: 3 gloads/thread (A 2 rounds of 128 rows, B 1 round); ring-3 slot
// proof as r5; steady vmcnt(3) (newest stage in flight), vmcnt(0) last.
template <int EPI>
__global__ __launch_bounds__(512, 4) void gemm_e(const ushort* __restrict__ A,
                                                 const ushort* __restrict__ Bt,
                                                 const float* __restrict__ bias,
                                                 const float* __restrict__ inF,
                                                 float* __restrict__ outF,
                                                 ushort* __restrict__ outB,
                                                 int M, int N, int K,
                                                 const float* __restrict__ tab) {
    __shared__ ushort AsF[3 * 8192] __attribute__((aligned(16)));  // ring-3, 48 KB
    __shared__ ushort BsF[3 * 4096] __attribute__((aligned(16)));  // ring-3, 24 KB
    int tid = threadIdx.x;
    int w = tid >> 6, lane = tid & 63;        // w in 0..7
    int wm = (w >> 1) * 64;                   // 0,64,128,192
    int wn = (w & 1) * 64;                    // 0 or 64

    // ---- bijective XCD swizzle (m204)
    int nbx = gridDim.x;
    int nwg = nbx * gridDim.y;
    int orig = blockIdx.y * nbx + blockIdx.x;
    int q8 = nwg >> 3, r8 = nwg & 7;
    int xcd = orig & 7, loc = orig >> 3;
    int id = (xcd < r8) ? xcd * (q8 + 1) + loc : r8 * (q8 + 1) + (xcd - r8) * q8 + loc;
    int m0 = (id / nbx) * 256;
    int n0 = (id % nbx) * 128;

    // ---- staging: 512 threads; round = 128 rows (8 waves x 16). A: 2 rounds, B: 1.
    int srow = tid >> 2;                          // 0..127
    int scol = ((tid & 3) ^ ((srow >> 1) & 3)) * 8;
    int rA0 = m0 + srow;        if (rA0 >= M) rA0 = M - 1;
    int rA1 = m0 + 128 + srow;  if (rA1 >= M) rA1 = M - 1;
    const ushort* gA0 = A + (size_t)rA0 * K + scol;
    const ushort* gA1 = A + (size_t)rA1 * K + scol;
    const ushort* gB0 = Bt + (size_t)(n0 + srow) * K + scol;
    int dwz = w * 512;   // wave-uniform dest within a 128-row round (16 rows/wave)
    int swA = 0, swB = 0;

#define STAGEE() do {                                                          \
        gload16(gA0, &AsF[swA + dwz]);                                         \
        gload16(gA1, &AsF[swA + 4096 + dwz]);                                  \
        gload16(gB0, &BsF[swB + dwz]);                                         \
        gA0 += 32; gA1 += 32; gB0 += 32;                                       \
        swA += 8192; if (swA == 24576) swA = 0;                                \
        swB += 4096; if (swB == 12288) swB = 0; } while (0)

    // ---- fragment read offsets (same verified chunk-xor swizzle; wm/i*16 do
    //      not touch row bits 1-2)
    int l15 = lane & 15, lq = lane >> 4;
    int sw = (lq ^ ((l15 >> 1) & 3)) * 8;
    int aoff = (wm + l15) * 32 + sw;
    int boff = (wn + l15) * 32 + sw;
    int roffA = 0, roffB = 0;

    int NT = K >> 5;
    STAGEE(); STAGEE();

    f32x4 acc[4][4] = {};

    for (int t = 0; t < NT; ++t) {
        if (t < NT - 1) asm volatile("s_waitcnt vmcnt(3)" ::: "memory");
        else            asm volatile("s_waitcnt vmcnt(0)" ::: "memory");
        __builtin_amdgcn_s_barrier();
        short8 a[4], b[4];
        #pragma unroll
        for (int i = 0; i < 4; i++) a[i] = *(const short8*)&AsF[roffA + aoff + i * 512];
        #pragma unroll
        for (int j = 0; j < 4; j++) b[j] = *(const short8*)&BsF[roffB + boff + j * 512];
        if (t + 2 < NT) STAGEE();          // into slot (t-1)%3, provably dead
        __builtin_amdgcn_s_setprio(1);
        #pragma unroll
        for (int i = 0; i < 4; i++)
            #pragma unroll
            for (int j = 0; j < 4; j++)
                acc[i][j] = __builtin_amdgcn_mfma_f32_16x16x32_bf16(a[i], b[j], acc[i][j], 0, 0, 0);
        __builtin_amdgcn_s_setprio(0);
        roffA += 8192; if (roffA == 24576) roffA = 0;
        roffB += 4096; if (roffB == 12288) roffB = 0;
    }
#undef STAGEE

    // ---- epilogue; C frag layout: row = lq*4+rr, col = l15
    int cr = lq * 4;
    int cc = l15;
    if (EPI == 0) {
        bool ropeReg = (n0 + wn) < 1024;
        int gnb = n0 + wn + cc;
        float bb0 = bias[gnb], bb1 = bias[gnb + 16], bb2 = bias[gnb + 32], bb3 = bias[gnb + 48];
        #pragma unroll
        for (int i = 0; i < 4; i++) {
            #pragma unroll
            for (int rr = 0; rr < 4; rr++) {
                int gm = m0 + wm + i * 16 + cr + rr;
                if (gm >= M) continue;
                int n = gm % NTOK;
                float v0 = acc[i][0][rr] + bb0;
                float v1 = acc[i][1][rr] + bb1;
                float v2 = acc[i][2][rr] + bb2;
                float v3 = acc[i][3][rr] + bb3;
                if (ropeReg && n > 0) {
                    const float* tt = tab + (size_t)(n - 1) * 64 + cc;
                    float cx = tt[0], sx = tt[16], cy = tt[32], sy = tt[48];
                    float y0 = v0 * cx - v1 * sx;
                    float y1 = v0 * sx + v1 * cx;
                    float y2 = v2 * cy - v3 * sy;
                    float y3 = v2 * sy + v3 * cy;
                    v0 = y0; v1 = y1; v2 = y2; v3 = y3;
                }
                size_t o = (size_t)gm * N + gnb;
                outB[o]      = f2bf(v0);
                outB[o + 16] = f2bf(v1);
                outB[o + 32] = f2bf(v2);
                outB[o + 48] = f2bf(v3);
            }
        }
    } else {
        #pragma unroll
        for (int i = 0; i < 4; i++) {
            #pragma unroll
            for (int rr = 0; rr < 4; rr++) {
                int gm = m0 + wm + i * 16 + cr + rr;
                if (gm >= M) continue;
                #pragma unroll
                for (int j = 0; j < 4; j++) {
                    int gn = n0 + wn + j * 16 + cc;
                    float v = acc[i][j][rr] + bias[gn];
                    size_t o = (size_t)gm * N + gn;
                    if (EPI == 1) {
                        outF[o] = inF[o] + v;
                    } else {
                        outB[o] = f2bf(gelu_fast(v));
                    }
                }
            }
        }
    }
}

// ---------------- MFMA attention: block = (batch,head), 384 threads = 6 waves.
__global__ __launch_bounds__(384) void attn_kernel(const ushort* __restrict__ qkv,
                                                   ushort* __restrict__ out) {
    __shared__ ushort SU[13824] __attribute__((aligned(16)));  // Qb | Kb, later Pb
    __shared__ ushort Vt[6656]  __attribute__((aligned(16)));  // V^T [64][104]
    int bh = blockIdx.x;
    int b = bh >> 3, h = bh & 7;
    int tid = threadIdx.x;
    size_t base = (size_t)b * NTOK * 1536 + h * 64;

    for (int it = tid; it < 1536; it += 384) {
        int mat = (it >= 768) ? 1 : 0;
        int item = it - mat * 768;
        int n = item >> 3, g = item & 7;
        short8 v = {};
        if (n < NTOK)
            v = *(const short8*)&qkv[base + (size_t)n * 1536 + mat * 512 + g * 8];
        *(short8*)&SU[mat * 6912 + n * 72 + g * 8] = v;
    }
    for (int it = tid; it < 768; it += 384) {
        int n = it % 96;
        int d0 = (it / 96) * 8;
        short8 v = {};
        if (n < NTOK)
            v = *(const short8*)&qkv[base + (size_t)n * 1536 + 1024 + d0];
        #pragma unroll
        for (int j = 0; j < 8; j++)
            Vt[(d0 + j) * 104 + n] = (ushort)v[j];
    }
    __syncthreads();

    int wid = tid >> 6;
    int lane = tid & 63;
    int q = lane >> 4, c = lane & 15;
    int i0 = wid * 16;

    f32x4 acc[6] = {};
    #pragma unroll
    for (int kk = 0; kk < 2; kk++) {
        short8 aq = *(const short8*)&SU[(i0 + c) * 72 + kk * 32 + q * 8];
        #pragma unroll
        for (int t = 0; t < 6; t++) {
            short8 bk = *(const short8*)&SU[6912 + (t * 16 + c) * 72 + kk * 32 + q * 8];
            acc[t] = __builtin_amdgcn_mfma_f32_16x16x32_bf16(aq, bk, acc[t], 0, 0, 0);
        }
    }
    __syncthreads();

    #pragma unroll
    for (int r = 0; r < 4; r++) {
        int i = i0 + q * 4 + r;
        int si = (i == 0) ? 3 : (i < 5 ? 1 : (i < 21 ? 2 : 3));
        float vs[6];
        float m = -1e30f;
        #pragma unroll
        for (int t = 0; t < 6; t++) {
            int j = t * 16 + c;
            int sj = (j == 0) ? si : (j < 5 ? 1 : (j < 21 ? 2 : (j < NTOK ? 3 : -1)));
            float v = (sj == si) ? acc[t][r] * 0.125f : -1e30f;
            vs[t] = v;
            m = fmaxf(m, v);
        }
        #pragma unroll
        for (int mk = 8; mk; mk >>= 1) m = fmaxf(m, __shfl_xor(m, mk));
        float s = 0.f, ps[6];
        #pragma unroll
        for (int t = 0; t < 6; t++) { ps[t] = __expf(vs[t] - m); s += ps[t]; }
        #pragma unroll
        for (int mk = 8; mk; mk >>= 1) s += __shfl_xor(s, mk);
        float inv = 1.0f / s;
        #pragma unroll
        for (int t = 0; t < 6; t++)
            SU[i * 104 + t * 16 + c] = f2bf(ps[t] * inv);
    }
    __syncthreads();

    f32x4 o2[4] = {};
    #pragma unroll
    for (int kk = 0; kk < 3; kk++) {
        short8 ap = *(const short8*)&SU[(i0 + c) * 104 + kk * 32 + q * 8];
        #pragma unroll
        for (int nt = 0; nt < 4; nt++) {
            short8 bv = *(const short8*)&Vt[(nt * 16 + c) * 104 + kk * 32 + q * 8];
            o2[nt] = __builtin_amdgcn_mfma_f32_16x16x32_bf16(ap, bv, o2[nt], 0, 0, 0);
        }
    }
    size_t orow = (size_t)b * NTOK;
    #pragma unroll
    for (int nt = 0; nt < 4; nt++) {
        #pragma unroll
        for (int r = 0; r < 4; r++) {
            int i = i0 + q * 4 + r;
            if (i < NTOK)
                out[(orow + i) * DIMX + h * 64 + nt * 16 + c] = f2bf(o2[nt][r]);
        }
    }
}

extern "C" void kernel_launch(void* const* d_in, const int* in_sizes, int n_in,
                              void* d_out, int out_size, void* d_ws, size_t ws_size,
                              hipStream_t stream) {
    const float* x_in    = (const float*)d_in[0];
    const float* coords  = (const float*)d_in[1];
    const float* ln1_g   = (const float*)d_in[2];
    const float* ln1_b   = (const float*)d_in[3];
    const float* qkv_w   = (const float*)d_in[4];
    const float* qkv_b   = (const float*)d_in[5];
    const float* proj_w  = (const float*)d_in[6];
    const float* proj_b  = (const float*)d_in[7];
    const float* ln2_g   = (const float*)d_in[8];
    const float* ln2_b   = (const float*)d_in[9];
    const float* fc1_w   = (const float*)d_in[10];
    const float* fc1_b   = (const float*)d_in[11];
    const float* fc2_w   = (const float*)d_in[12];
    const float* fc2_b   = (const float*)d_in[13];

    char* ws = (char*)d_ws;
    size_t off = 0;
    auto alloc = [&](size_t bytes) -> void* {
        void* p = ws + off;
        off += (bytes + 255) & ~(size_t)255;
        return p;
    };
    auto asz = [](size_t b) { return (b + 255) & ~(size_t)255; };

    const size_t WPL = 512 * 1536 + 512 * 512 + 512 * 2048 + 2048 * 512; // 3,145,728

    size_t fixed = asz(WPL * DEPTH * sizeof(ushort)) + asz(84 * 64 * sizeof(float));
    int Bc = 1024;
    while (Bc > 4) {
        size_t rc = (size_t)Bc * NTOK;
        size_t need = fixed + asz(rc * DIMX * sizeof(ushort)) + asz(rc * MLP_H * sizeof(ushort));
        if (need <= ws_size) break;
        Bc >>= 1;
    }
    size_t Rc = (size_t)Bc * NTOK;

    ushort* wt   = (ushort*)alloc(WPL * DEPTH * sizeof(ushort));
    float*  tab  = (float*)alloc(84 * 64 * sizeof(float));
    ushort* hbuf = (ushort*)alloc(Rc * DIMX * sizeof(ushort));   // ln out / attn out (aliased)
    ushort* big  = (ushort*)alloc(Rc * MLP_H * sizeof(ushort));  // qkv out / mlp out (aliased)

    rope_table<<<84, 16, 0, stream>>>(coords, tab);

    dim3 tb(32, 8);
    for (int l = 0; l < DEPTH; l++) {
        ushort* wl = wt + (size_t)l * WPL;
        transpose_bf16<<<dim3(1536 / 32, 512 / 32), tb, 0, stream>>>(
            qkv_w + (size_t)l * 512 * 1536, wl, 512, 1536);
        transpose_bf16<<<dim3(512 / 32, 512 / 32), tb, 0, stream>>>(
            proj_w + (size_t)l * 512 * 512, wl + 786432, 512, 512);
        transpose_bf16<<<dim3(2048 / 32, 512 / 32), tb, 0, stream>>>(
            fc1_w + (size_t)l * 512 * 2048, wl + 1048576, 512, 2048);
        transpose_bf16<<<dim3(512 / 32, 2048 / 32), tb, 0, stream>>>(
            fc2_w + (size_t)l * 2048 * 512, wl + 2097152, 2048, 512);
    }

    int mt256 = (int)(Rc / 256);
    int lnblocks = (int)(Rc / 4);
    for (int c = 0; c < BATCH / Bc; c++) {
        float* xc = (float*)d_out + (size_t)c * Rc * DIMX;
        const float* xin_c = x_in + (size_t)c * Rc * DIMX;
        int Mc = (int)Rc;
        for (int l = 0; l < DEPTH; l++) {
            ushort* wl = wt + (size_t)l * WPL;
            // layer 0 reads the input tensor directly (no startup memcpy);
            // proj of layer 0 writes residual x_in + proj into xc.
            const float* xsrc = (l == 0) ? xin_c : xc;
            ln_kernel<<<lnblocks, 256, 0, stream>>>(
                xsrc, ln1_g + l * 512, ln1_b + l * 512, hbuf);
            gemm_wide<0><<<dim3(1536 / 128, mt256), 256, 0, stream>>>(
                hbuf, wl, qkv_b + (size_t)l * 1536, nullptr, nullptr, big,
                Mc, 1536, 512, tab);
            attn_kernel<<<Bc * 8, 384, 0, stream>>>(big, hbuf);
            gemm_wide<1><<<dim3(512 / 128, mt256), 256, 0, stream>>>(
                hbuf, wl + 786432, proj_b + (size_t)l * 512, xsrc, xc, nullptr,
                Mc, 512, 512, nullptr);
            ln_kernel<<<lnblocks, 256, 0, stream>>>(
                xc, ln2_g + l * 512, ln2_b + l * 512, hbuf);
            // FC1: class-E probe (8 waves, 64x64 wave tile, 16 waves/CU) vs
            // FC2's class B at equal FLOP.
            gemm_e<2><<<dim3(2048 / 128, mt256), 512, 0, stream>>>(
                hbuf, wl + 1048576, fc1_b + (size_t)l * 2048, nullptr, nullptr,
                big, Mc, 2048, 512, nullptr);
            gemm_wide<1><<<dim3(512 / 128, mt256), 256, 0, stream>>>(
                big, wl + 2097152, fc2_b + (size_t)l * 512, xc, xc, nullptr,
                Mc, 512, 2048, nullptr);
        }
    }
}

// Round 11
// 6655.861 us; speedup vs baseline: 1.0831x; 1.0234x over previous
//
#include <hip/hip_runtime.h>
#include <hip/hip_bf16.h>
#include <math.h>

#define DIMX 512
#define NTOK 85
#define BATCH 1024
#define M_ROWS (BATCH * NTOK)   // 87040
#define MLP_H 2048
#define DEPTH 6

typedef __attribute__((ext_vector_type(8))) short short8;
typedef __attribute__((ext_vector_type(4))) float f32x4;

__device__ inline float bf2f(ushort u) {
    union { unsigned int i; float f; } v; v.i = ((unsigned int)u) << 16; return v.f;
}
__device__ inline ushort f2bf(float f) {
    __hip_bfloat16 h = __float2bfloat16(f);
    union { __hip_bfloat16 h; ushort u; } v; v.h = h; return v.u;
}
__device__ inline unsigned int pack2(float a, float b) {
    return (unsigned int)f2bf(a) | ((unsigned int)f2bf(b) << 16);
}
// cheap GELU: v * sigmoid(1.5957691*(v + 0.044715 v^3)); max abs err ~5e-4 (< bf16 ulp there)
__device__ inline float gelu_fast(float v) {
    float u = 1.5957691f * fmaf(0.044715f * v, v * v, v);
    return v / (1.0f + __expf(-u));
}

// async global->LDS, 16B per lane. lds dest must be wave-uniform; HW adds lane*16.
__device__ inline void gload16(const ushort* g, ushort* lds) {
    __builtin_amdgcn_global_load_lds(
        (const __attribute__((address_space(1))) unsigned int*)g,
        (__attribute__((address_space(3))) unsigned int*)lds, 16, 0, 0);
}

// ---------------- weight transpose + convert: in [K][N] f32 -> out [N][K] bf16
__global__ __launch_bounds__(256) void transpose_bf16(const float* __restrict__ in,
                                                      ushort* __restrict__ out,
                                                      int K, int N) {
    __shared__ float tile[32][33];
    int n0 = blockIdx.x * 32, k0 = blockIdx.y * 32;
    int tx = threadIdx.x, ty = threadIdx.y;   // 32 x 8
    #pragma unroll
    for (int j = 0; j < 32; j += 8)
        tile[ty + j][tx] = in[(size_t)(k0 + ty + j) * N + n0 + tx];
    __syncthreads();
    #pragma unroll
    for (int j = 0; j < 32; j += 8)
        out[(size_t)(n0 + ty + j) * K + k0 + tx] = f2bf(tile[tx][ty + j]);
}

// ---------------- RoPE cos/sin table
__global__ void rope_table(const float* __restrict__ coords, float* __restrict__ tab) {
    int t = blockIdx.x;       // 0..83
    int idx = threadIdx.x;    // 0..15
    float freq = expf(-(float)idx * (2.302585093f / 16.0f));
    float twopi = 6.283185307179586f;
    float ax = coords[t * 2 + 0] * freq * twopi;
    float ay = coords[t * 2 + 1] * freq * twopi;
    tab[t * 64 + idx]      = cosf(ax);
    tab[t * 64 + 16 + idx] = sinf(ax);
    tab[t * 64 + 32 + idx] = cosf(ay);
    tab[t * 64 + 48 + idx] = sinf(ay);
}

// ---------------- LayerNorm: f32 row of 512 -> bf16 out, wave per row
__global__ __launch_bounds__(256) void ln_kernel(const float* __restrict__ x,
                                                 const float* __restrict__ g,
                                                 const float* __restrict__ bta,
                                                 ushort* __restrict__ out) {
    int w = threadIdx.x >> 6, lane = threadIdx.x & 63;
    size_t row = (size_t)blockIdx.x * 4 + w;
    const float* xr = x + row * DIMX;
    int c = lane * 8;
    float4 v0 = *(const float4*)(xr + c);
    float4 v1 = *(const float4*)(xr + c + 4);
    float s = v0.x + v0.y + v0.z + v0.w + v1.x + v1.y + v1.z + v1.w;
    #pragma unroll
    for (int m = 32; m; m >>= 1) s += __shfl_xor(s, m);
    float mu = s * (1.0f / 512.0f);
    float d0 = v0.x - mu, d1 = v0.y - mu, d2 = v0.z - mu, d3 = v0.w - mu;
    float d4 = v1.x - mu, d5 = v1.y - mu, d6 = v1.z - mu, d7 = v1.w - mu;
    float q = d0*d0 + d1*d1 + d2*d2 + d3*d3 + d4*d4 + d5*d5 + d6*d6 + d7*d7;
    #pragma unroll
    for (int m = 32; m; m >>= 1) q += __shfl_xor(q, m);
    float rs = rsqrtf(q * (1.0f / 512.0f) + 1e-5f);
    float4 g0 = *(const float4*)(g + c), g1 = *(const float4*)(g + c + 4);
    float4 b0 = *(const float4*)(bta + c), b1 = *(const float4*)(bta + c + 4);
    uint4 o;
    o.x = pack2(d0 * rs * g0.x + b0.x, d1 * rs * g0.y + b0.y);
    o.y = pack2(d2 * rs * g0.z + b0.z, d3 * rs * g0.w + b0.w);
    o.z = pack2(d4 * rs * g1.x + b1.x, d5 * rs * g1.y + b1.y);
    o.w = pack2(d6 * rs * g1.z + b1.z, d7 * rs * g1.w + b1.w);
    *(uint4*)&out[row * DIMX + c] = o;
}

// ---------------- GEMM class E (proven r10, FC1 +13% vs class B): 256x128
// tile, BK=32, ring-3 LDS (72 KB), 512 threads = 8 waves (4M x 2N), wave tile
// 64x64 (acc[4][4] = 64 AGPR + ~56 VGPR -> 4 waves/SIMD -> 16 waves/CU,
// 2 blocks co-resident). Class B's traffic ratio at class A's occupancy;
// occupancy (not schedule) is what covers the step-phase latency.
// Staging: 3 gloads/thread; ring-3 slot proof (r5); vmcnt(3) steady, (0) last.
// EPI 0: bf16 rope(acc+bias); EPI 1: f32 = inF + acc+bias; EPI 2: bf16 gelu
template <int EPI>
__global__ __launch_bounds__(512, 4) void gemm_e(const ushort* __restrict__ A,
                                                 const ushort* __restrict__ Bt,
                                                 const float* __restrict__ bias,
                                                 const float* __restrict__ inF,
                                                 float* __restrict__ outF,
                                                 ushort* __restrict__ outB,
                                                 int M, int N, int K,
                                                 const float* __restrict__ tab) {
    __shared__ ushort AsF[3 * 8192] __attribute__((aligned(16)));  // ring-3, 48 KB
    __shared__ ushort BsF[3 * 4096] __attribute__((aligned(16)));  // ring-3, 24 KB
    int tid = threadIdx.x;
    int w = tid >> 6, lane = tid & 63;        // w in 0..7
    int wm = (w >> 1) * 64;                   // 0,64,128,192
    int wn = (w & 1) * 64;                    // 0 or 64

    // ---- bijective XCD swizzle (m204)
    int nbx = gridDim.x;
    int nwg = nbx * gridDim.y;
    int orig = blockIdx.y * nbx + blockIdx.x;
    int q8 = nwg >> 3, r8 = nwg & 7;
    int xcd = orig & 7, loc = orig >> 3;
    int id = (xcd < r8) ? xcd * (q8 + 1) + loc : r8 * (q8 + 1) + (xcd - r8) * q8 + loc;
    int m0 = (id / nbx) * 256;
    int n0 = (id % nbx) * 128;

    // ---- staging: 512 threads; round = 128 rows (8 waves x 16). A: 2 rounds, B: 1.
    int srow = tid >> 2;                          // 0..127
    int scol = ((tid & 3) ^ ((srow >> 1) & 3)) * 8;
    int rA0 = m0 + srow;        if (rA0 >= M) rA0 = M - 1;
    int rA1 = m0 + 128 + srow;  if (rA1 >= M) rA1 = M - 1;
    const ushort* gA0 = A + (size_t)rA0 * K + scol;
    const ushort* gA1 = A + (size_t)rA1 * K + scol;
    const ushort* gB0 = Bt + (size_t)(n0 + srow) * K + scol;
    int dwz = w * 512;   // wave-uniform dest within a 128-row round (16 rows/wave)
    int swA = 0, swB = 0;

#define STAGEE() do {                                                          \
        gload16(gA0, &AsF[swA + dwz]);                                         \
        gload16(gA1, &AsF[swA + 4096 + dwz]);                                  \
        gload16(gB0, &BsF[swB + dwz]);                                         \
        gA0 += 32; gA1 += 32; gB0 += 32;                                       \
        swA += 8192; if (swA == 24576) swA = 0;                                \
        swB += 4096; if (swB == 12288) swB = 0; } while (0)

    // ---- fragment read offsets (verified chunk-xor swizzle)
    int l15 = lane & 15, lq = lane >> 4;
    int sw = (lq ^ ((l15 >> 1) & 3)) * 8;
    int aoff = (wm + l15) * 32 + sw;
    int boff = (wn + l15) * 32 + sw;
    int roffA = 0, roffB = 0;

    int NT = K >> 5;
    STAGEE(); STAGEE();

    f32x4 acc[4][4] = {};

    for (int t = 0; t < NT; ++t) {
        if (t < NT - 1) asm volatile("s_waitcnt vmcnt(3)" ::: "memory");
        else            asm volatile("s_waitcnt vmcnt(0)" ::: "memory");
        __builtin_amdgcn_s_barrier();
        short8 a[4], b[4];
        #pragma unroll
        for (int i = 0; i < 4; i++) a[i] = *(const short8*)&AsF[roffA + aoff + i * 512];
        #pragma unroll
        for (int j = 0; j < 4; j++) b[j] = *(const short8*)&BsF[roffB + boff + j * 512];
        if (t + 2 < NT) STAGEE();          // into slot (t-1)%3, provably dead
        __builtin_amdgcn_s_setprio(1);
        #pragma unroll
        for (int i = 0; i < 4; i++)
            #pragma unroll
            for (int j = 0; j < 4; j++)
                acc[i][j] = __builtin_amdgcn_mfma_f32_16x16x32_bf16(a[i], b[j], acc[i][j], 0, 0, 0);
        __builtin_amdgcn_s_setprio(0);
        roffA += 8192; if (roffA == 24576) roffA = 0;
        roffB += 4096; if (roffB == 12288) roffB = 0;
    }
#undef STAGEE

    // ---- epilogue; C frag layout: row = lq*4+rr, col = l15
    int cr = lq * 4;
    int cc = l15;
    if (EPI == 0) {
        // QKV + fused RoPE: head = 64 cols = wave stripe (n0+wn is a multiple
        // of 64); pairs (idx,idx+16) are nfrag 0/1 and 2/3 of the SAME thread.
        bool ropeReg = (n0 + wn) < 1024;   // Q or K region (V >= 1024), wave-uniform
        int gnb = n0 + wn + cc;
        float bb0 = bias[gnb], bb1 = bias[gnb + 16], bb2 = bias[gnb + 32], bb3 = bias[gnb + 48];
        #pragma unroll
        for (int i = 0; i < 4; i++) {
            #pragma unroll
            for (int rr = 0; rr < 4; rr++) {
                int gm = m0 + wm + i * 16 + cr + rr;
                if (gm >= M) continue;
                int n = gm % NTOK;
                float v0 = acc[i][0][rr] + bb0;
                float v1 = acc[i][1][rr] + bb1;
                float v2 = acc[i][2][rr] + bb2;
                float v3 = acc[i][3][rr] + bb3;
                if (ropeReg && n > 0) {
                    const float* tt = tab + (size_t)(n - 1) * 64 + cc;
                    float cx = tt[0], sx = tt[16], cy = tt[32], sy = tt[48];
                    float y0 = v0 * cx - v1 * sx;
                    float y1 = v0 * sx + v1 * cx;
                    float y2 = v2 * cy - v3 * sy;
                    float y3 = v2 * sy + v3 * cy;
                    v0 = y0; v1 = y1; v2 = y2; v3 = y3;
                }
                size_t o = (size_t)gm * N + gnb;
                outB[o]      = f2bf(v0);
                outB[o + 16] = f2bf(v1);
                outB[o + 32] = f2bf(v2);
                outB[o + 48] = f2bf(v3);
            }
        }
    } else {
        #pragma unroll
        for (int i = 0; i < 4; i++) {
            #pragma unroll
            for (int rr = 0; rr < 4; rr++) {
                int gm = m0 + wm + i * 16 + cr + rr;
                if (gm >= M) continue;
                #pragma unroll
                for (int j = 0; j < 4; j++) {
                    int gn = n0 + wn + j * 16 + cc;
                    float v = acc[i][j][rr] + bias[gn];
                    size_t o = (size_t)gm * N + gn;
                    if (EPI == 1) {
                        outF[o] = inF[o] + v;
                    } else {
                        outB[o] = f2bf(gelu_fast(v));
                    }
                }
            }
        }
    }
}

// ---------------- MFMA attention: block = (batch,head), 384 threads = 6 waves.
__global__ __launch_bounds__(384) void attn_kernel(const ushort* __restrict__ qkv,
                                                   ushort* __restrict__ out) {
    __shared__ ushort SU[13824] __attribute__((aligned(16)));  // Qb | Kb, later Pb
    __shared__ ushort Vt[6656]  __attribute__((aligned(16)));  // V^T [64][104]
    int bh = blockIdx.x;
    int b = bh >> 3, h = bh & 7;
    int tid = threadIdx.x;
    size_t base = (size_t)b * NTOK * 1536 + h * 64;

    for (int it = tid; it < 1536; it += 384) {
        int mat = (it >= 768) ? 1 : 0;
        int item = it - mat * 768;
        int n = item >> 3, g = item & 7;
        short8 v = {};
        if (n < NTOK)
            v = *(const short8*)&qkv[base + (size_t)n * 1536 + mat * 512 + g * 8];
        *(short8*)&SU[mat * 6912 + n * 72 + g * 8] = v;
    }
    for (int it = tid; it < 768; it += 384) {
        int n = it % 96;
        int d0 = (it / 96) * 8;
        short8 v = {};
        if (n < NTOK)
            v = *(const short8*)&qkv[base + (size_t)n * 1536 + 1024 + d0];
        #pragma unroll
        for (int j = 0; j < 8; j++)
            Vt[(d0 + j) * 104 + n] = (ushort)v[j];
    }
    __syncthreads();

    int wid = tid >> 6;
    int lane = tid & 63;
    int q = lane >> 4, c = lane & 15;
    int i0 = wid * 16;

    f32x4 acc[6] = {};
    #pragma unroll
    for (int kk = 0; kk < 2; kk++) {
        short8 aq = *(const short8*)&SU[(i0 + c) * 72 + kk * 32 + q * 8];
        #pragma unroll
        for (int t = 0; t < 6; t++) {
            short8 bk = *(const short8*)&SU[6912 + (t * 16 + c) * 72 + kk * 32 + q * 8];
            acc[t] = __builtin_amdgcn_mfma_f32_16x16x32_bf16(aq, bk, acc[t], 0, 0, 0);
        }
    }
    __syncthreads();

    #pragma unroll
    for (int r = 0; r < 4; r++) {
        int i = i0 + q * 4 + r;
        int si = (i == 0) ? 3 : (i < 5 ? 1 : (i < 21 ? 2 : 3));
        float vs[6];
        float m = -1e30f;
        #pragma unroll
        for (int t = 0; t < 6; t++) {
            int j = t * 16 + c;
            int sj = (j == 0) ? si : (j < 5 ? 1 : (j < 21 ? 2 : (j < NTOK ? 3 : -1)));
            float v = (sj == si) ? acc[t][r] * 0.125f : -1e30f;
            vs[t] = v;
            m = fmaxf(m, v);
        }
        #pragma unroll
        for (int mk = 8; mk; mk >>= 1) m = fmaxf(m, __shfl_xor(m, mk));
        float s = 0.f, ps[6];
        #pragma unroll
        for (int t = 0; t < 6; t++) { ps[t] = __expf(vs[t] - m); s += ps[t]; }
        #pragma unroll
        for (int mk = 8; mk; mk >>= 1) s += __shfl_xor(s, mk);
        float inv = 1.0f / s;
        #pragma unroll
        for (int t = 0; t < 6; t++)
            SU[i * 104 + t * 16 + c] = f2bf(ps[t] * inv);
    }
    __syncthreads();

    f32x4 o2[4] = {};
    #pragma unroll
    for (int kk = 0; kk < 3; kk++) {
        short8 ap = *(const short8*)&SU[(i0 + c) * 104 + kk * 32 + q * 8];
        #pragma unroll
        for (int nt = 0; nt < 4; nt++) {
            short8 bv = *(const short8*)&Vt[(nt * 16 + c) * 104 + kk * 32 + q * 8];
            o2[nt] = __builtin_amdgcn_mfma_f32_16x16x32_bf16(ap, bv, o2[nt], 0, 0, 0);
        }
    }
    size_t orow = (size_t)b * NTOK;
    #pragma unroll
    for (int nt = 0; nt < 4; nt++) {
        #pragma unroll
        for (int r = 0; r < 4; r++) {
            int i = i0 + q * 4 + r;
            if (i < NTOK)
                out[(orow + i) * DIMX + h * 64 + nt * 16 + c] = f2bf(o2[nt][r]);
        }
    }
}

extern "C" void kernel_launch(void* const* d_in, const int* in_sizes, int n_in,
                              void* d_out, int out_size, void* d_ws, size_t ws_size,
                              hipStream_t stream) {
    const float* x_in    = (const float*)d_in[0];
    const float* coords  = (const float*)d_in[1];
    const float* ln1_g   = (const float*)d_in[2];
    const float* ln1_b   = (const float*)d_in[3];
    const float* qkv_w   = (const float*)d_in[4];
    const float* qkv_b   = (const float*)d_in[5];
    const float* proj_w  = (const float*)d_in[6];
    const float* proj_b  = (const float*)d_in[7];
    const float* ln2_g   = (const float*)d_in[8];
    const float* ln2_b   = (const float*)d_in[9];
    const float* fc1_w   = (const float*)d_in[10];
    const float* fc1_b   = (const float*)d_in[11];
    const float* fc2_w   = (const float*)d_in[12];
    const float* fc2_b   = (const float*)d_in[13];

    char* ws = (char*)d_ws;
    size_t off = 0;
    auto alloc = [&](size_t bytes) -> void* {
        void* p = ws + off;
        off += (bytes + 255) & ~(size_t)255;
        return p;
    };
    auto asz = [](size_t b) { return (b + 255) & ~(size_t)255; };

    const size_t WPL = 512 * 1536 + 512 * 512 + 512 * 2048 + 2048 * 512; // 3,145,728

    size_t fixed = asz(WPL * DEPTH * sizeof(ushort)) + asz(84 * 64 * sizeof(float));
    int Bc = 1024;
    while (Bc > 4) {
        size_t rc = (size_t)Bc * NTOK;
        size_t need = fixed + asz(rc * DIMX * sizeof(ushort)) + asz(rc * MLP_H * sizeof(ushort));
        if (need <= ws_size) break;
        Bc >>= 1;
    }
    size_t Rc = (size_t)Bc * NTOK;

    ushort* wt   = (ushort*)alloc(WPL * DEPTH * sizeof(ushort));
    float*  tab  = (float*)alloc(84 * 64 * sizeof(float));
    ushort* hbuf = (ushort*)alloc(Rc * DIMX * sizeof(ushort));   // ln out / attn out (aliased)
    ushort* big  = (ushort*)alloc(Rc * MLP_H * sizeof(ushort));  // qkv out / mlp out (aliased)

    rope_table<<<84, 16, 0, stream>>>(coords, tab);

    dim3 tb(32, 8);
    for (int l = 0; l < DEPTH; l++) {
        ushort* wl = wt + (size_t)l * WPL;
        transpose_bf16<<<dim3(1536 / 32, 512 / 32), tb, 0, stream>>>(
            qkv_w + (size_t)l * 512 * 1536, wl, 512, 1536);
        transpose_bf16<<<dim3(512 / 32, 512 / 32), tb, 0, stream>>>(
            proj_w + (size_t)l * 512 * 512, wl + 786432, 512, 512);
        transpose_bf16<<<dim3(2048 / 32, 512 / 32), tb, 0, stream>>>(
            fc1_w + (size_t)l * 512 * 2048, wl + 1048576, 512, 2048);
        transpose_bf16<<<dim3(512 / 32, 2048 / 32), tb, 0, stream>>>(
            fc2_w + (size_t)l * 2048 * 512, wl + 2097152, 2048, 512);
    }

    int mt256 = (int)(Rc / 256);
    int lnblocks = (int)(Rc / 4);
    for (int c = 0; c < BATCH / Bc; c++) {
        float* xc = (float*)d_out + (size_t)c * Rc * DIMX;
        const float* xin_c = x_in + (size_t)c * Rc * DIMX;
        int Mc = (int)Rc;
        for (int l = 0; l < DEPTH; l++) {
            ushort* wl = wt + (size_t)l * WPL;
            // layer 0 reads the input tensor directly (no startup memcpy);
            // proj of layer 0 writes residual x_in + proj into xc.
            const float* xsrc = (l == 0) ? xin_c : xc;
            ln_kernel<<<lnblocks, 256, 0, stream>>>(
                xsrc, ln1_g + l * 512, ln1_b + l * 512, hbuf);
            gemm_e<0><<<dim3(1536 / 128, mt256), 512, 0, stream>>>(
                hbuf, wl, qkv_b + (size_t)l * 1536, nullptr, nullptr, big,
                Mc, 1536, 512, tab);
            attn_kernel<<<Bc * 8, 384, 0, stream>>>(big, hbuf);
            gemm_e<1><<<dim3(512 / 128, mt256), 512, 0, stream>>>(
                hbuf, wl + 786432, proj_b + (size_t)l * 512, xsrc, xc, nullptr,
                Mc, 512, 512, nullptr);
            ln_kernel<<<lnblocks, 256, 0, stream>>>(
                xc, ln2_g + l * 512, ln2_b + l * 512, hbuf);
            gemm_e<2><<<dim3(2048 / 128, mt256), 512, 0, stream>>>(
                hbuf, wl + 1048576, fc1_b + (size_t)l * 2048, nullptr, nullptr,
                big, Mc, 2048, 512, nullptr);
            gemm_e<1><<<dim3(512 / 128, mt256), 512, 0, stream>>>(
                big, wl + 2097152, fc2_b + (size_t)l * 512, xc, xc, nullptr,
                Mc, 512, 2048, nullptr);
        }
    }
}